// Round 10
// baseline (125.835 us; speedup 1.0000x reference)
//
#include <hip/hip_runtime.h>
#include <hip/hip_bf16.h>
#include <math.h>

// MAB: q=QWq^T+bq; k=KWk^T+bk; v=KWv^T+bv; per-head softmax(qk^T/16)v + q-residual;
// LN0; +relu(GEMM Wo); LN1.  B=4, N=2048, D=256, H=4, Dh=64.
// Round 10: attn v7 -- 32 q-rows/wave (halves LDS read amplification), KV-split
// x4, single-buffered LDS (64KB, 2 blocks/CU), split K/V register prefetch.
// Softmax = validated no-max exp2 + cvt_pk/permlane in-register P (per qt).
// ws (8 MB): [0,4MB) k bf16 [8192][256]; [4,8MB) v_t bf16 [16][64][2048].

typedef __attribute__((ext_vector_type(8))) short bf16x8;
typedef __attribute__((ext_vector_type(4))) float f32x4;

static __device__ __forceinline__ unsigned short f2bf(float x) {
  return __bfloat16_as_ushort(__float2bfloat16(x));
}
static __device__ __forceinline__ int pk2(float lo, float hi) {
  return (int)((unsigned)f2bf(lo) | ((unsigned)f2bf(hi) << 16));
}
static __device__ __forceinline__ float exp2_fast(float x) {
  float r; asm("v_exp_f32 %0, %1" : "=v"(r) : "v"(x)); return r;
}

#define SWZ(row, col) ((col) ^ (((row) & 7) << 3))

// ---------------------------------------------------------------------------
// Unified projection kernel, all bf16 MFMA. grid (4, 128, 3), 256 threads.
// z=0: q -> fp32 qout; z=1: k -> bf16 kbf; z=2: v -> bf16 transposed vtb.
// ---------------------------------------------------------------------------
__global__ __launch_bounds__(256, 2) void proj_kernel(
    const float* __restrict__ Q, const float* __restrict__ K,
    const float* __restrict__ Wq, const float* __restrict__ bq,
    const float* __restrict__ Wk, const float* __restrict__ bk,
    const float* __restrict__ Wv, const float* __restrict__ bv,
    float* __restrict__ qout, unsigned short* __restrict__ kbf,
    unsigned short* __restrict__ vtb)
{
  __shared__ __align__(16) unsigned short Ab[64][64];
  __shared__ __align__(16) unsigned short Wb[64][64];
  const int tid = threadIdx.x;
  const int z = blockIdx.z;
  const int bn = blockIdx.x, bm = blockIdx.y;

  const float* A    = (z == 0) ? Q  : K;
  const float* W    = (z == 0) ? Wq : ((z == 1) ? Wk : Wv);
  const float* bias = (z == 0) ? bq : ((z == 1) ? bk : bv);

  const int wid = tid >> 6, lane = tid & 63;
  const int l15 = lane & 15, g = lane >> 4;
  const int wr = wid >> 1, wc = wid & 1;
  const float* Ablk = A + (size_t)bm * 64 * 256;
  const float* Wblk = W + (size_t)bn * 64 * 256;

  const int sr = tid >> 2, sc = (tid & 3) * 16;
  const int c0 = SWZ(sr, sc), c1 = SWZ(sr, sc + 8);

  f32x4 acc[2][2];
  #pragma unroll
  for (int i = 0; i < 2; ++i)
    #pragma unroll
    for (int j = 0; j < 2; ++j)
      #pragma unroll
      for (int r = 0; r < 4; ++r) acc[i][j][r] = 0.f;

  float4 aR[4], wR[4];
  #pragma unroll
  for (int u = 0; u < 4; ++u) {
    aR[u] = *(const float4*)(Ablk + (size_t)sr*256 + sc + u*4);
    wR[u] = *(const float4*)(Wblk + (size_t)sr*256 + sc + u*4);
  }

  for (int k0 = 0; k0 < 256; k0 += 64) {
    if (k0) __syncthreads();
    int4 pa0 = { pk2(aR[0].x,aR[0].y), pk2(aR[0].z,aR[0].w),
                 pk2(aR[1].x,aR[1].y), pk2(aR[1].z,aR[1].w) };
    int4 pa1 = { pk2(aR[2].x,aR[2].y), pk2(aR[2].z,aR[2].w),
                 pk2(aR[3].x,aR[3].y), pk2(aR[3].z,aR[3].w) };
    int4 pw0 = { pk2(wR[0].x,wR[0].y), pk2(wR[0].z,wR[0].w),
                 pk2(wR[1].x,wR[1].y), pk2(wR[1].z,wR[1].w) };
    int4 pw1 = { pk2(wR[2].x,wR[2].y), pk2(wR[2].z,wR[2].w),
                 pk2(wR[3].x,wR[3].y), pk2(wR[3].z,wR[3].w) };
    *(int4*)&Ab[sr][c0] = pa0;  *(int4*)&Ab[sr][c1] = pa1;
    *(int4*)&Wb[sr][c0] = pw0;  *(int4*)&Wb[sr][c1] = pw1;
    __syncthreads();
    if (k0 < 192) {
      #pragma unroll
      for (int u = 0; u < 4; ++u) {
        aR[u] = *(const float4*)(Ablk + (size_t)sr*256 + (k0+64) + sc + u*4);
        wR[u] = *(const float4*)(Wblk + (size_t)sr*256 + (k0+64) + sc + u*4);
      }
    }
    const unsigned short (*Ta)[64] = (z == 2) ? Wb : Ab;
    const unsigned short (*Tb)[64] = (z == 2) ? Ab : Wb;
    __builtin_amdgcn_s_setprio(1);
    #pragma unroll
    for (int kc = 0; kc < 64; kc += 32) {
      bf16x8 af[2], bf_[2];
      #pragma unroll
      for (int i = 0; i < 2; ++i) {
        int ra = wr*32 + i*16 + l15;
        int rb = wc*32 + i*16 + l15;
        af[i]  = *(const bf16x8*)&Ta[ra][SWZ(ra, kc + g*8)];
        bf_[i] = *(const bf16x8*)&Tb[rb][SWZ(rb, kc + g*8)];
      }
      #pragma unroll
      for (int i = 0; i < 2; ++i)
        #pragma unroll
        for (int j = 0; j < 2; ++j)
          acc[i][j] = __builtin_amdgcn_mfma_f32_16x16x32_bf16(af[i], bf_[j], acc[i][j], 0, 0, 0);
    }
    __builtin_amdgcn_s_setprio(0);
  }

  if (z == 2) {
    const int bvb = bm >> 5;
    const int n0 = (bm & 31) * 64 + wc*32;
    #pragma unroll
    for (int di = 0; di < 2; ++di)
      #pragma unroll
      for (int r = 0; r < 4; ++r) {
        int d = wr*32 + di*16 + g*4 + r;
        float bvs = bias[bn*64 + d];
        #pragma unroll
        for (int ni = 0; ni < 2; ++ni) {
          float c = acc[di][ni][r] + bvs;
          vtb[((size_t)(bvb*4 + bn)*64 + d)*2048 + n0 + ni*16 + l15] = f2bf(c);
        }
      }
    return;
  }

  const int gm = bm*64 + wr*32, ge = bn*64 + wc*32;
  float bv0 = bias[ge + l15], bv1 = bias[ge + 16 + l15];
  #pragma unroll
  for (int mi = 0; mi < 2; ++mi)
    #pragma unroll
    for (int r = 0; r < 4; ++r) {
      int row = gm + mi*16 + g*4 + r;
      #pragma unroll
      for (int ei = 0; ei < 2; ++ei) {
        float c = acc[mi][ei][r] + (ei ? bv1 : bv0);
        if (z == 0) qout[(size_t)row*256 + ge + ei*16 + l15] = c;
        else        kbf [(size_t)row*256 + ge + ei*16 + l15] = f2bf(c);
      }
    }
}

// ---------------------------------------------------------------------------
// MFMA flash attention v7.
// 512 thr = 8 waves: grp = wid>>1 (KV quarter, 8 tiles of 64), qw = wid&1
// (32 q-rows/wave as 2 q-subtiles qt). Single-buffered LDS K[4]/V[4] = 64 KB;
// register prefetch: K loads after the stage barrier, V loads after softmax.
// In-register P via cvt_pk + permlane swaps (validated). No-max exp2 softmax.
// 4-way merge (plain sums) in LDS. 512 blocks, XCD-swizzled.
// ---------------------------------------------------------------------------
typedef unsigned short tileKV_t[64][64];

__global__ __launch_bounds__(512, 4) void attn_mfma7(
    const float* __restrict__ q,
    const unsigned short* __restrict__ kb,
    const unsigned short* __restrict__ vt,
    float* __restrict__ o)
{
  extern __shared__ __align__(16) char smem_dyn[];
  tileKV_t* Ks = (tileKV_t*)smem_dyn;             // [4 grp], 32 KB
  tileKV_t* Vt = (tileKV_t*)(smem_dyn + 32768);   // [4 grp], 32 KB

  const int tid = threadIdx.x;
  const int wid = tid >> 6;
  const int grp = wid >> 1;        // 0..3 KV quarter
  const int qw  = wid & 1;         // q half within block
  const int lane = tid & 63;
  const int l15 = lane & 15;
  const int g = lane >> 4;
  const int lin = blockIdx.x;
  const int xcd = lin & 7, idx = lin >> 3;
  const int bh = xcd * 2 + (idx >> 5);
  const int qb = idx & 31;
  const int b = bh >> 2, h = bh & 3;

  const float qscale = 0.0625f * 1.44269504089f;   // 1/sqrt(256) * log2(e)
  bf16x8 qf[2][2];                                 // [qt][ds]
  #pragma unroll
  for (int qt = 0; qt < 2; ++qt) {
    const float* qp = q + ((size_t)(b*2048 + qb*64 + qw*32 + qt*16 + l15))*256 + h*64;
    #pragma unroll
    for (int ds_ = 0; ds_ < 2; ++ds_) {
      union { bf16x8 v; unsigned short s[8]; } tmp;
      #pragma unroll
      for (int j = 0; j < 8; ++j) tmp.s[j] = f2bf(qp[ds_*32 + g*8 + j] * qscale);
      qf[qt][ds_] = tmp.v;
    }
  }

  // staging geometry: the grp's wave pair (128 threads) stages K+V tile
  const int gt = tid & 127;
  const int srow = gt >> 1;               // 0..63
  const int chs  = (gt & 1) * 32;         // short-col base
  int wcol[4];
  #pragma unroll
  for (int j = 0; j < 4; ++j) wcol[j] = SWZ(srow, chs + 8*j);
  const unsigned short* kgp = kb + ((size_t)(b*2048 + grp*512 + srow))*256 + h*64 + chs;
  const unsigned short* vgp = vt + ((size_t)bh*64 + srow)*2048 + grp*512 + chs;

  f32x4 oa[2][4];
  #pragma unroll
  for (int qt = 0; qt < 2; ++qt)
    #pragma unroll
    for (int mt = 0; mt < 4; ++mt)
      #pragma unroll
      for (int r = 0; r < 4; ++r) oa[qt][mt][r] = 0.f;
  float l0 = 0.f, l1 = 0.f;

  int4 kR[4], vR[4];
  #pragma unroll
  for (int j = 0; j < 4; ++j) {
    kR[j] = *(const int4*)(kgp + 8*j);
    vR[j] = *(const int4*)(vgp + 8*j);
  }

  for (int t = 0; t < 8; ++t) {
    if (t) __syncthreads();                 // previous tile's compute done
    #pragma unroll
    for (int j = 0; j < 4; ++j) *(int4*)&Ks[grp][srow][wcol[j]] = kR[j];
    #pragma unroll
    for (int j = 0; j < 4; ++j) *(int4*)&Vt[grp][srow][wcol[j]] = vR[j];
    __syncthreads();                        // tile visible (drains lgkm)
    if (t < 7) {                            // K prefetch under QK+softmax
      #pragma unroll
      for (int j = 0; j < 4; ++j)
        kR[j] = *(const int4*)(kgp + (size_t)(t+1)*64*256 + 8*j);
    }

    // ---- S^T: 64 k' x 32 q per wave (A-frag reads shared across qt)
    f32x4 sa[2][4];
    #pragma unroll
    for (int qt = 0; qt < 2; ++qt)
      #pragma unroll
      for (int mt = 0; mt < 4; ++mt)
        #pragma unroll
        for (int r = 0; r < 4; ++r) sa[qt][mt][r] = 0.f;
    __builtin_amdgcn_s_setprio(1);
    #pragma unroll
    for (int ds_ = 0; ds_ < 2; ++ds_) {
      #pragma unroll
      for (int mt = 0; mt < 4; ++mt) {
        bf16x8 af = *(const bf16x8*)&Ks[grp][mt*16 + l15][SWZ(l15, ds_*32 + g*8)];
        sa[0][mt] = __builtin_amdgcn_mfma_f32_16x16x32_bf16(af, qf[0][ds_], sa[0][mt], 0, 0, 0);
        sa[1][mt] = __builtin_amdgcn_mfma_f32_16x16x32_bf16(af, qf[1][ds_], sa[1][mt], 0, 0, 0);
      }
    }
    __builtin_amdgcn_s_setprio(0);

    // ---- no-max softmax per qt: p = exp2(S'), pack bf16 pairs
    unsigned pk01[2][4], pk23[2][4];
    #pragma unroll
    for (int qt = 0; qt < 2; ++qt) {
      float ps = 0.f;
      #pragma unroll
      for (int mt = 0; mt < 4; ++mt) {
        float p0 = exp2_fast(sa[qt][mt][0]);
        float p1 = exp2_fast(sa[qt][mt][1]);
        float p2 = exp2_fast(sa[qt][mt][2]);
        float p3 = exp2_fast(sa[qt][mt][3]);
        ps += (p0 + p1) + (p2 + p3);
        pk01[qt][mt] = (unsigned)pk2(p0, p1);
        pk23[qt][mt] = (unsigned)pk2(p2, p3);
      }
      ps += __shfl_xor(ps, 16, 64);
      ps += __shfl_xor(ps, 32, 64);
      if (qt == 0) l0 += ps; else l1 += ps;
    }

    if (t < 7) {                            // V prefetch under PV
      #pragma unroll
      for (int j = 0; j < 4; ++j)
        vR[j] = *(const int4*)(vgp + (t+1)*64 + 8*j);
    }

    // ---- O^T += V^T P^T (in-register P fragments; V-frag shared across qt)
    __builtin_amdgcn_s_setprio(1);
    #pragma unroll
    for (int ks_ = 0; ks_ < 2; ++ks_) {
      bf16x8 pf[2];
      #pragma unroll
      for (int qt = 0; qt < 2; ++qt) {
        unsigned a0 = pk01[qt][2*ks_], b0 = pk01[qt][2*ks_ + 1];
        unsigned a1 = pk23[qt][2*ks_], b1 = pk23[qt][2*ks_ + 1];
        asm volatile("v_permlane32_swap_b32 %0, %1" : "+v"(a0), "+v"(b0));
        asm volatile("v_permlane16_swap_b32 %0, %1" : "+v"(a0), "+v"(b0));
        asm volatile("v_permlane32_swap_b32 %0, %1" : "+v"(a1), "+v"(b1));
        asm volatile("v_permlane16_swap_b32 %0, %1" : "+v"(a1), "+v"(b1));
        int4 pw = { (int)a0, (int)a1, (int)b0, (int)b1 };  // j01, j23, j45, j67
        pf[qt] = __builtin_bit_cast(bf16x8, pw);
      }
      #pragma unroll
      for (int mt = 0; mt < 4; ++mt) {
        bf16x8 vf = *(const bf16x8*)&Vt[grp][mt*16 + l15][SWZ(l15, ks_*32 + g*8)];
        oa[0][mt] = __builtin_amdgcn_mfma_f32_16x16x32_bf16(vf, pf[0], oa[0][mt], 0, 0, 0);
        oa[1][mt] = __builtin_amdgcn_mfma_f32_16x16x32_bf16(vf, pf[1], oa[1][mt], 0, 0, 0);
      }
    }
    __builtin_amdgcn_s_setprio(0);
  }

  // ---- 4-way merge (plain sums; tiles dead, reuse LDS). Stride 65 vs bank hits.
  __syncthreads();
  float* cob = (float*)smem_dyn;                   // 3 x [64][65] f32
  float* cml = (float*)(smem_dyn + 3*64*65*4);     // 3 x 64 f32
  if (grp > 0) {
    const int gi = grp - 1;
    #pragma unroll
    for (int qt = 0; qt < 2; ++qt) {
      int qloc = qw*32 + qt*16 + l15;
      #pragma unroll
      for (int mt = 0; mt < 4; ++mt)
        #pragma unroll
        for (int r = 0; r < 4; ++r)
          cob[(gi*64 + mt*16 + g*4 + r)*65 + qloc] = oa[qt][mt][r];
      cml[gi*64 + qloc] = (qt == 0) ? l0 : l1;
    }
  }
  __syncthreads();
  if (grp == 0) {
    #pragma unroll
    for (int qt = 0; qt < 2; ++qt) {
      int qloc = qw*32 + qt*16 + l15;
      float lsum = (qt == 0 ? l0 : l1)
                 + cml[qloc] + cml[64 + qloc] + cml[128 + qloc];
      float linv = 1.0f / lsum;
      float* op = o + ((size_t)(b*2048 + qb*64 + qloc))*256 + h*64;
      #pragma unroll
      for (int mt = 0; mt < 4; ++mt) {
        int dbase = mt*16 + g*4;
        float4 qv = *(const float4*)(op + dbase);
        float4 st;
        #pragma unroll
        for (int r = 0; r < 4; ++r) {
          float s = oa[qt][mt][r]
                  + cob[(0*64 + dbase + r)*65 + qloc]
                  + cob[(1*64 + dbase + r)*65 + qloc]
                  + cob[(2*64 + dbase + r)*65 + qloc];
          ((float*)&st)[r] = ((const float*)&qv)[r] + s * linv;
        }
        *(float4*)(op + dbase) = st;
      }
    }
  }
}

// ---------------------------------------------------------------------------
// fused_out: LN0 + [res + relu(LN0 @ Wo^T + bo)] + LN1, in-place over d_out.
// ---------------------------------------------------------------------------
__global__ __launch_bounds__(512) void fused_out(
    const float* __restrict__ x, const float* __restrict__ Wo,
    const float* __restrict__ bo,
    const float* __restrict__ g0v, const float* __restrict__ b0v,
    const float* __restrict__ g1v, const float* __restrict__ b1v,
    float* __restrict__ y)
{
  __shared__ __align__(16) unsigned short As[32][256];
  __shared__ __align__(16) unsigned short Ws[256][64];
  __shared__ float mu_[32], rs_[32];
  float* P = (float*)&Ws[0][0];

  const int tid = threadIdx.x;
  const int w = tid >> 6, lane = tid & 63;
  const int l15 = lane & 15, g = lane >> 4;
  const int r0 = blockIdx.x * 32;

  {
    float4 g4 = *(const float4*)(g0v + lane*4);
    float4 b4 = *(const float4*)(b0v + lane*4);
    #pragma unroll
    for (int rr = 0; rr < 4; ++rr) {
      int m = w*4 + rr;
      const float* xr = x + (size_t)(r0 + m) * 256;
      float4 v = *(const float4*)(xr + lane*4);
      float s = v.x + v.y + v.z + v.w;
      #pragma unroll
      for (int mk = 1; mk <= 32; mk <<= 1) s += __shfl_xor(s, mk, 64);
      float mu = s * (1.0f/256.0f);
      float dx = v.x-mu, dy = v.y-mu, dz = v.z-mu, dw = v.w-mu;
      float qq = dx*dx + dy*dy + dz*dz + dw*dw;
      #pragma unroll
      for (int mk = 1; mk <= 32; mk <<= 1) qq += __shfl_xor(qq, mk, 64);
      float rstd = rsqrtf(qq * (1.0f/256.0f) + 1e-5f);
      if (lane == 0) { mu_[m] = mu; rs_[m] = rstd; }
      float nx = dx*rstd*g4.x + b4.x;
      float ny = dy*rstd*g4.y + b4.y;
      float nz = dz*rstd*g4.z + b4.z;
      float nw = dw*rstd*g4.w + b4.w;
      int2 pv = { pk2(nx, ny), pk2(nz, nw) };
      int col = lane*4;
      *(int2*)&As[m][SWZ(m, col)] = pv;
    }
  }
  __syncthreads();

  const int m0 = (w >> 2) * 16;
  const int e0 = (w & 3) * 64;
  f32x4 acc4[4];
  #pragma unroll
  for (int j = 0; j < 4; ++j)
    #pragma unroll
    for (int r = 0; r < 4; ++r) acc4[j][r] = 0.f;

  for (int k0 = 0; k0 < 256; k0 += 64) {
    if (k0) __syncthreads();
    {
      const int ch = tid & 7;
      const int er = tid >> 3;
      #pragma unroll
      for (int p = 0; p < 4; ++p) {
        int e = p*64 + er;
        const float* wp = Wo + (size_t)e*256 + k0 + ch*8;
        float4 u0 = *(const float4*)wp;
        float4 u1 = *(const float4*)(wp + 4);
        int4 pk = { pk2(u0.x,u0.y), pk2(u0.z,u0.w), pk2(u1.x,u1.y), pk2(u1.z,u1.w) };
        *(int4*)&Ws[e][SWZ(e, ch*8)] = pk;
      }
    }
    __syncthreads();
    __builtin_amdgcn_s_setprio(1);
    #pragma unroll
    for (int ds_ = 0; ds_ < 2; ++ds_) {
      int ma = m0 + l15;
      bf16x8 af = *(const bf16x8*)&As[ma][SWZ(ma, k0 + ds_*32 + g*8)];
      #pragma unroll
      for (int j = 0; j < 4; ++j) {
        int er = e0 + j*16 + l15;
        bf16x8 bfv = *(const bf16x8*)&Ws[er][SWZ(er, ds_*32 + g*8)];
        acc4[j] = __builtin_amdgcn_mfma_f32_16x16x32_bf16(af, bfv, acc4[j], 0, 0, 0);
      }
    }
    __builtin_amdgcn_s_setprio(0);
  }
  __syncthreads();

  #pragma unroll
  for (int j = 0; j < 4; ++j) {
    int e = e0 + j*16 + l15;
    float bov = bo[e], g0e = g0v[e], b0e = b0v[e];
    #pragma unroll
    for (int r = 0; r < 4; ++r) {
      int m = m0 + g*4 + r;
      float xv = x[(size_t)(r0 + m)*256 + e];
      float resv = (xv - mu_[m]) * rs_[m] * g0e + b0e;
      float val = acc4[j][r] + bov;
      P[m*256 + e] = resv + fmaxf(val, 0.f);
    }
  }
  __syncthreads();

  {
    float4 g4 = *(const float4*)(g1v + lane*4);
    float4 b4 = *(const float4*)(b1v + lane*4);
    #pragma unroll
    for (int rr = 0; rr < 4; ++rr) {
      int m = w*4 + rr;
      float4 v = *(const float4*)&P[m*256 + lane*4];
      float s = v.x + v.y + v.z + v.w;
      #pragma unroll
      for (int mk = 1; mk <= 32; mk <<= 1) s += __shfl_xor(s, mk, 64);
      float mu = s * (1.0f/256.0f);
      float dx = v.x-mu, dy = v.y-mu, dz = v.z-mu, dw = v.w-mu;
      float qq = dx*dx + dy*dy + dz*dz + dw*dw;
      #pragma unroll
      for (int mk = 1; mk <= 32; mk <<= 1) qq += __shfl_xor(qq, mk, 64);
      float rstd = rsqrtf(qq * (1.0f/256.0f) + 1e-5f);
      float4 o;
      o.x = dx*rstd*g4.x + b4.x; o.y = dy*rstd*g4.y + b4.y;
      o.z = dz*rstd*g4.z + b4.z; o.w = dw*rstd*g4.w + b4.w;
      *(float4*)(y + (size_t)(r0 + m)*256 + lane*4) = o;
    }
  }
}

// ---------------------------------------------------------------------------
extern "C" void kernel_launch(void* const* d_in, const int* in_sizes, int n_in,
                              void* d_out, int out_size, void* d_ws, size_t ws_size,
                              hipStream_t stream) {
  const float* Q  = (const float*)d_in[0];
  const float* K  = (const float*)d_in[1];
  const float* Wq = (const float*)d_in[2];
  const float* bq = (const float*)d_in[3];
  const float* Wk = (const float*)d_in[4];
  const float* bk = (const float*)d_in[5];
  const float* Wv = (const float*)d_in[6];
  const float* bv = (const float*)d_in[7];
  const float* Wo = (const float*)d_in[8];
  const float* bo = (const float*)d_in[9];
  const float* g0 = (const float*)d_in[10];
  const float* b0 = (const float*)d_in[11];
  const float* g1 = (const float*)d_in[12];
  const float* b1 = (const float*)d_in[13];
  float* out = (float*)d_out;

  const size_t SZ = (size_t)4 * 2048 * 256;
  if (ws_size < 2 * SZ * sizeof(unsigned short)) return;  // need 8 MB

  unsigned short* kbf = (unsigned short*)d_ws;
  unsigned short* vtb = kbf + SZ;

  const int ATTN_LDS = 65536;  // 64 KB dynamic (K[4] 32K + V[4] 32K, single buf)
  hipFuncSetAttribute((const void*)attn_mfma7,
                      hipFuncAttributeMaxDynamicSharedMemorySize, ATTN_LDS);

  proj_kernel<<<dim3(4, 128, 3), dim3(256), 0, stream>>>(
      Q, K, Wq, bq, Wk, bk, Wv, bv, out, kbf, vtb);
  attn_mfma7<<<dim3(512), dim3(512), ATTN_LDS, stream>>>(out, kbf, vtb, out);
  fused_out<<<dim3(256), dim3(512), 0, stream>>>(out, Wo, bo, g0, b0, g1, b1, out);
}

// Round 11
// 69.718 us; speedup vs baseline: 1.8049x; 1.8049x over previous
//
#include <hip/hip_runtime.h>
#include <hip/hip_bf16.h>
#include <math.h>

// MAB: q=QWq^T+bq; k=KWk^T+bk; v=KWv^T+bv; per-head softmax(qk^T/16)v + q-residual;
// LN0; +relu(GEMM Wo); LN1.  B=4, N=2048, D=256, H=4, Dh=64.
// Round 11: attn v8 -- 32 q-rows/wave via global_load_lds staging (no staging
// VGPRs -> no spills), 256-thr blocks (2 KV-groups x 2 q-waves), double-buffered
// 64KB LDS, pre-swizzled global source + linear LDS dest (rule #21).
// ws (8 MB): [0,4MB) k bf16 [8192][256]; [4,8MB) v_t bf16 [16][64][2048].

typedef __attribute__((ext_vector_type(8))) short bf16x8;
typedef __attribute__((ext_vector_type(4))) float f32x4;

static __device__ __forceinline__ unsigned short f2bf(float x) {
  return __bfloat16_as_ushort(__float2bfloat16(x));
}
static __device__ __forceinline__ int pk2(float lo, float hi) {
  return (int)((unsigned)f2bf(lo) | ((unsigned)f2bf(hi) << 16));
}
static __device__ __forceinline__ float exp2_fast(float x) {
  float r; asm("v_exp_f32 %0, %1" : "=v"(r) : "v"(x)); return r;
}
static __device__ __forceinline__ void gload_lds16(const void* g, void* lds) {
  __builtin_amdgcn_global_load_lds(
      (const __attribute__((address_space(1))) unsigned int*)g,
      (__attribute__((address_space(3))) unsigned int*)lds, 16, 0, 0);
}

#define SWZ(row, col) ((col) ^ (((row) & 7) << 3))

// ---------------------------------------------------------------------------
// Unified projection kernel, all bf16 MFMA. grid (4, 128, 3), 256 threads.
// z=0: q -> fp32 qout; z=1: k -> bf16 kbf; z=2: v -> bf16 transposed vtb.
// (unchanged from round 9, validated)
// ---------------------------------------------------------------------------
__global__ __launch_bounds__(256, 2) void proj_kernel(
    const float* __restrict__ Q, const float* __restrict__ K,
    const float* __restrict__ Wq, const float* __restrict__ bq,
    const float* __restrict__ Wk, const float* __restrict__ bk,
    const float* __restrict__ Wv, const float* __restrict__ bv,
    float* __restrict__ qout, unsigned short* __restrict__ kbf,
    unsigned short* __restrict__ vtb)
{
  __shared__ __align__(16) unsigned short Ab[64][64];
  __shared__ __align__(16) unsigned short Wb[64][64];
  const int tid = threadIdx.x;
  const int z = blockIdx.z;
  const int bn = blockIdx.x, bm = blockIdx.y;

  const float* A    = (z == 0) ? Q  : K;
  const float* W    = (z == 0) ? Wq : ((z == 1) ? Wk : Wv);
  const float* bias = (z == 0) ? bq : ((z == 1) ? bk : bv);

  const int wid = tid >> 6, lane = tid & 63;
  const int l15 = lane & 15, g = lane >> 4;
  const int wr = wid >> 1, wc = wid & 1;
  const float* Ablk = A + (size_t)bm * 64 * 256;
  const float* Wblk = W + (size_t)bn * 64 * 256;

  const int sr = tid >> 2, sc = (tid & 3) * 16;
  const int c0 = SWZ(sr, sc), c1 = SWZ(sr, sc + 8);

  f32x4 acc[2][2];
  #pragma unroll
  for (int i = 0; i < 2; ++i)
    #pragma unroll
    for (int j = 0; j < 2; ++j)
      #pragma unroll
      for (int r = 0; r < 4; ++r) acc[i][j][r] = 0.f;

  float4 aR[4], wR[4];
  #pragma unroll
  for (int u = 0; u < 4; ++u) {
    aR[u] = *(const float4*)(Ablk + (size_t)sr*256 + sc + u*4);
    wR[u] = *(const float4*)(Wblk + (size_t)sr*256 + sc + u*4);
  }

  for (int k0 = 0; k0 < 256; k0 += 64) {
    if (k0) __syncthreads();
    int4 pa0 = { pk2(aR[0].x,aR[0].y), pk2(aR[0].z,aR[0].w),
                 pk2(aR[1].x,aR[1].y), pk2(aR[1].z,aR[1].w) };
    int4 pa1 = { pk2(aR[2].x,aR[2].y), pk2(aR[2].z,aR[2].w),
                 pk2(aR[3].x,aR[3].y), pk2(aR[3].z,aR[3].w) };
    int4 pw0 = { pk2(wR[0].x,wR[0].y), pk2(wR[0].z,wR[0].w),
                 pk2(wR[1].x,wR[1].y), pk2(wR[1].z,wR[1].w) };
    int4 pw1 = { pk2(wR[2].x,wR[2].y), pk2(wR[2].z,wR[2].w),
                 pk2(wR[3].x,wR[3].y), pk2(wR[3].z,wR[3].w) };
    *(int4*)&Ab[sr][c0] = pa0;  *(int4*)&Ab[sr][c1] = pa1;
    *(int4*)&Wb[sr][c0] = pw0;  *(int4*)&Wb[sr][c1] = pw1;
    __syncthreads();
    if (k0 < 192) {
      #pragma unroll
      for (int u = 0; u < 4; ++u) {
        aR[u] = *(const float4*)(Ablk + (size_t)sr*256 + (k0+64) + sc + u*4);
        wR[u] = *(const float4*)(Wblk + (size_t)sr*256 + (k0+64) + sc + u*4);
      }
    }
    const unsigned short (*Ta)[64] = (z == 2) ? Wb : Ab;
    const unsigned short (*Tb)[64] = (z == 2) ? Ab : Wb;
    __builtin_amdgcn_s_setprio(1);
    #pragma unroll
    for (int kc = 0; kc < 64; kc += 32) {
      bf16x8 af[2], bf_[2];
      #pragma unroll
      for (int i = 0; i < 2; ++i) {
        int ra = wr*32 + i*16 + l15;
        int rb = wc*32 + i*16 + l15;
        af[i]  = *(const bf16x8*)&Ta[ra][SWZ(ra, kc + g*8)];
        bf_[i] = *(const bf16x8*)&Tb[rb][SWZ(rb, kc + g*8)];
      }
      #pragma unroll
      for (int i = 0; i < 2; ++i)
        #pragma unroll
        for (int j = 0; j < 2; ++j)
          acc[i][j] = __builtin_amdgcn_mfma_f32_16x16x32_bf16(af[i], bf_[j], acc[i][j], 0, 0, 0);
    }
    __builtin_amdgcn_s_setprio(0);
  }

  if (z == 2) {
    const int bvb = bm >> 5;
    const int n0 = (bm & 31) * 64 + wc*32;
    #pragma unroll
    for (int di = 0; di < 2; ++di)
      #pragma unroll
      for (int r = 0; r < 4; ++r) {
        int d = wr*32 + di*16 + g*4 + r;
        float bvs = bias[bn*64 + d];
        #pragma unroll
        for (int ni = 0; ni < 2; ++ni) {
          float c = acc[di][ni][r] + bvs;
          vtb[((size_t)(bvb*4 + bn)*64 + d)*2048 + n0 + ni*16 + l15] = f2bf(c);
        }
      }
    return;
  }

  const int gm = bm*64 + wr*32, ge = bn*64 + wc*32;
  float bv0 = bias[ge + l15], bv1 = bias[ge + 16 + l15];
  #pragma unroll
  for (int mi = 0; mi < 2; ++mi)
    #pragma unroll
    for (int r = 0; r < 4; ++r) {
      int row = gm + mi*16 + g*4 + r;
      #pragma unroll
      for (int ei = 0; ei < 2; ++ei) {
        float c = acc[mi][ei][r] + (ei ? bv1 : bv0);
        if (z == 0) qout[(size_t)row*256 + ge + ei*16 + l15] = c;
        else        kbf [(size_t)row*256 + ge + ei*16 + l15] = f2bf(c);
      }
    }
}

// ---------------------------------------------------------------------------
// MFMA flash attention v8.
// 256 thr = 4 waves: grp = wid>>1 (KV half, 16 tiles), qw = wid&1 (32 q/wave).
// Staging via global_load_lds (async, no staging VGPRs): linear LDS dest,
// pre-swizzled global source chunk = (lane&7) ^ ((lane>>3)&7).
// LDS 64KB: K[2buf][2grp][64][64] + V same. One vmcnt(0)+barrier per tile.
// No-max exp2 softmax; in-register P via cvt_pk + permlane (validated).
// 512 blocks, XCD-swizzled. 2-way merge (plain sums).
// ---------------------------------------------------------------------------
__global__ __launch_bounds__(256, 2) void attn_mfma8(
    const float* __restrict__ q,
    const unsigned short* __restrict__ kb,
    const unsigned short* __restrict__ vt,
    float* __restrict__ o)
{
  extern __shared__ __align__(16) char smem_dyn[];
  // K tiles at (buf*2+grp)*8192; V tiles at 32768 + same.

  const int tid = threadIdx.x;
  const int wid = tid >> 6;        // 0..3
  const int grp = wid >> 1;        // KV half
  const int qw  = wid & 1;         // q half (32 rows)
  const int lane = tid & 63;
  const int l15 = lane & 15;
  const int g = lane >> 4;
  const int lin = blockIdx.x;
  const int xcd = lin & 7, idx = lin >> 3;
  const int bh = xcd * 2 + (idx >> 5);
  const int qb = idx & 31;
  const int b = bh >> 2, h = bh & 3;

  const float qscale = 0.0625f * 1.44269504089f;   // 1/sqrt(256) * log2(e)
  bf16x8 qf[2][2];                                 // [qt][ds]
  #pragma unroll
  for (int qt = 0; qt < 2; ++qt) {
    const float* qp = q + ((size_t)(b*2048 + qb*64 + qw*32 + qt*16 + l15))*256 + h*64;
    #pragma unroll
    for (int ds_ = 0; ds_ < 2; ++ds_) {
      union { bf16x8 v; unsigned short s[8]; } tmp;
      #pragma unroll
      for (int j = 0; j < 8; ++j) tmp.s[j] = f2bf(qp[ds_*32 + g*8 + j] * qscale);
      qf[qt][ds_] = tmp.v;
    }
  }

  // gload_lds lane geometry: issue covers 8 rows x 8 chunks (16B each).
  // LDS linear dest; global source chunk pre-swizzled so reads use SWZ().
  const int lrow = lane >> 3;                         // 0..7
  const int lchk = (lane & 7) ^ lrow;                 // pre-swizzled chunk
  const unsigned short* kL = kb
      + ((size_t)(b*2048 + grp*1024 + qw*32 + lrow))*256 + h*64 + lchk*8;
  const unsigned short* vL = vt
      + ((size_t)(bh*64 + qw*32 + lrow))*2048 + grp*1024 + lchk*8;
  const int ldsKb = grp*8192 + qw*4096;               // + buf*16384 + i*1024
  const int ldsVb = 32768 + grp*8192 + qw*4096;

#define STAGE8(tt, bb) do {                                                   \
    const size_t koff_ = (size_t)(tt)*64*256;                                 \
    const size_t voff_ = (size_t)(tt)*64;                                     \
    _Pragma("unroll")                                                         \
    for (int i_ = 0; i_ < 4; ++i_) {                                          \
      gload_lds16(kL + koff_ + (size_t)i_*8*256,                              \
                  smem_dyn + (bb)*16384 + ldsKb + i_*1024);                   \
      gload_lds16(vL + voff_ + (size_t)i_*8*2048,                             \
                  smem_dyn + (bb)*16384 + ldsVb + i_*1024);                   \
    }                                                                         \
  } while (0)

  f32x4 oa[2][4];
  #pragma unroll
  for (int qt = 0; qt < 2; ++qt)
    #pragma unroll
    for (int mt = 0; mt < 4; ++mt)
      #pragma unroll
      for (int r = 0; r < 4; ++r) oa[qt][mt][r] = 0.f;
  float l_[2] = {0.f, 0.f};

  // prologue: tile 0 -> buf 0
  STAGE8(0, 0);
  asm volatile("s_waitcnt vmcnt(0)" ::: "memory");
  __syncthreads();

  int cur = 0;
  for (int t = 0; t < 16; ++t) {
    if (t < 15) STAGE8(t + 1, cur ^ 1);   // async into other buffer

    const unsigned short (*Kc)[64] =
        (const unsigned short(*)[64])(smem_dyn + cur*16384 + grp*8192);
    const unsigned short (*Vc)[64] =
        (const unsigned short(*)[64])(smem_dyn + 32768 + cur*16384 + grp*8192);

    // ---- S^T: 64 k' x 32 q per wave (A-frag shared across qt)
    f32x4 sa[2][4];
    #pragma unroll
    for (int qt = 0; qt < 2; ++qt)
      #pragma unroll
      for (int mt = 0; mt < 4; ++mt)
        #pragma unroll
        for (int r = 0; r < 4; ++r) sa[qt][mt][r] = 0.f;
    __builtin_amdgcn_s_setprio(1);
    #pragma unroll
    for (int ds_ = 0; ds_ < 2; ++ds_) {
      #pragma unroll
      for (int mt = 0; mt < 4; ++mt) {
        bf16x8 af = *(const bf16x8*)&Kc[mt*16 + l15][SWZ(l15, ds_*32 + g*8)];
        sa[0][mt] = __builtin_amdgcn_mfma_f32_16x16x32_bf16(af, qf[0][ds_], sa[0][mt], 0, 0, 0);
        sa[1][mt] = __builtin_amdgcn_mfma_f32_16x16x32_bf16(af, qf[1][ds_], sa[1][mt], 0, 0, 0);
      }
    }
    __builtin_amdgcn_s_setprio(0);

    // ---- no-max softmax per qt (sa dies here -> pk regs)
    unsigned pk01[2][4], pk23[2][4];
    #pragma unroll
    for (int qt = 0; qt < 2; ++qt) {
      float ps = 0.f;
      #pragma unroll
      for (int mt = 0; mt < 4; ++mt) {
        float p0 = exp2_fast(sa[qt][mt][0]);
        float p1 = exp2_fast(sa[qt][mt][1]);
        float p2 = exp2_fast(sa[qt][mt][2]);
        float p3 = exp2_fast(sa[qt][mt][3]);
        ps += (p0 + p1) + (p2 + p3);
        pk01[qt][mt] = (unsigned)pk2(p0, p1);
        pk23[qt][mt] = (unsigned)pk2(p2, p3);
      }
      ps += __shfl_xor(ps, 16, 64);
      ps += __shfl_xor(ps, 32, 64);
      l_[qt] += ps;
    }

    // ---- O^T += V^T P^T (in-register P; V-frag shared across qt)
    __builtin_amdgcn_s_setprio(1);
    #pragma unroll
    for (int ks_ = 0; ks_ < 2; ++ks_) {
      bf16x8 pf[2];
      #pragma unroll
      for (int qt = 0; qt < 2; ++qt) {
        unsigned a0 = pk01[qt][2*ks_], b0 = pk01[qt][2*ks_ + 1];
        unsigned a1 = pk23[qt][2*ks_], b1 = pk23[qt][2*ks_ + 1];
        asm volatile("v_permlane32_swap_b32 %0, %1" : "+v"(a0), "+v"(b0));
        asm volatile("v_permlane16_swap_b32 %0, %1" : "+v"(a0), "+v"(b0));
        asm volatile("v_permlane32_swap_b32 %0, %1" : "+v"(a1), "+v"(b1));
        asm volatile("v_permlane16_swap_b32 %0, %1" : "+v"(a1), "+v"(b1));
        int4 pw = { (int)a0, (int)a1, (int)b0, (int)b1 };  // j01, j23, j45, j67
        pf[qt] = __builtin_bit_cast(bf16x8, pw);
      }
      #pragma unroll
      for (int mt = 0; mt < 4; ++mt) {
        bf16x8 vf = *(const bf16x8*)&Vc[mt*16 + l15][SWZ(l15, ks_*32 + g*8)];
        oa[0][mt] = __builtin_amdgcn_mfma_f32_16x16x32_bf16(vf, pf[0], oa[0][mt], 0, 0, 0);
        oa[1][mt] = __builtin_amdgcn_mfma_f32_16x16x32_bf16(vf, pf[1], oa[1][mt], 0, 0, 0);
      }
    }
    __builtin_amdgcn_s_setprio(0);

    // next buffer ready (loads had the whole compute phase); reads of cur done
    asm volatile("s_waitcnt vmcnt(0)" ::: "memory");
    __syncthreads();
    cur ^= 1;
  }
#undef STAGE8

  // ---- 2-way merge (plain sums; LDS tiles dead, reuse as f32 scratch)
  float* cob = (float*)smem_dyn;                   // [32][128] f32 (16 KB)
  float* cml = (float*)(smem_dyn + 32768);         // [2][128] f32
  const int ci = qw*64 + lane;                     // 0..127
  if (grp == 1) {
    #pragma unroll
    for (int qt = 0; qt < 2; ++qt) {
      #pragma unroll
      for (int mt = 0; mt < 4; ++mt)
        #pragma unroll
        for (int r = 0; r < 4; ++r)
          cob[(qt*16 + mt*4 + r)*128 + ci] = oa[qt][mt][r];
      cml[qt*128 + ci] = l_[qt];
    }
  }
  __syncthreads();
  if (grp == 0) {
    #pragma unroll
    for (int qt = 0; qt < 2; ++qt) {
      const int qloc = qw*32 + qt*16 + l15;
      float linv = 1.0f / (l_[qt] + cml[qt*128 + ci]);
      float* op = o + ((size_t)(b*2048 + qb*64 + qloc))*256 + h*64;
      #pragma unroll
      for (int mt = 0; mt < 4; ++mt) {
        int dbase = mt*16 + g*4;
        float4 qv = *(const float4*)(op + dbase);
        float4 st;
        st.x = qv.x + (oa[qt][mt][0] + cob[(qt*16 + mt*4 + 0)*128 + ci]) * linv;
        st.y = qv.y + (oa[qt][mt][1] + cob[(qt*16 + mt*4 + 1)*128 + ci]) * linv;
        st.z = qv.z + (oa[qt][mt][2] + cob[(qt*16 + mt*4 + 2)*128 + ci]) * linv;
        st.w = qv.w + (oa[qt][mt][3] + cob[(qt*16 + mt*4 + 3)*128 + ci]) * linv;
        *(float4*)(op + dbase) = st;
      }
    }
  }
}

// ---------------------------------------------------------------------------
// fused_out: LN0 + [res + relu(LN0 @ Wo^T + bo)] + LN1, in-place over d_out.
// (unchanged from round 9, validated)
// ---------------------------------------------------------------------------
__global__ __launch_bounds__(512) void fused_out(
    const float* __restrict__ x, const float* __restrict__ Wo,
    const float* __restrict__ bo,
    const float* __restrict__ g0v, const float* __restrict__ b0v,
    const float* __restrict__ g1v, const float* __restrict__ b1v,
    float* __restrict__ y)
{
  __shared__ __align__(16) unsigned short As[32][256];
  __shared__ __align__(16) unsigned short Ws[256][64];
  __shared__ float mu_[32], rs_[32];
  float* P = (float*)&Ws[0][0];

  const int tid = threadIdx.x;
  const int w = tid >> 6, lane = tid & 63;
  const int l15 = lane & 15, g = lane >> 4;
  const int r0 = blockIdx.x * 32;

  {
    float4 g4 = *(const float4*)(g0v + lane*4);
    float4 b4 = *(const float4*)(b0v + lane*4);
    #pragma unroll
    for (int rr = 0; rr < 4; ++rr) {
      int m = w*4 + rr;
      const float* xr = x + (size_t)(r0 + m) * 256;
      float4 v = *(const float4*)(xr + lane*4);
      float s = v.x + v.y + v.z + v.w;
      #pragma unroll
      for (int mk = 1; mk <= 32; mk <<= 1) s += __shfl_xor(s, mk, 64);
      float mu = s * (1.0f/256.0f);
      float dx = v.x-mu, dy = v.y-mu, dz = v.z-mu, dw = v.w-mu;
      float qq = dx*dx + dy*dy + dz*dz + dw*dw;
      #pragma unroll
      for (int mk = 1; mk <= 32; mk <<= 1) qq += __shfl_xor(qq, mk, 64);
      float rstd = rsqrtf(qq * (1.0f/256.0f) + 1e-5f);
      if (lane == 0) { mu_[m] = mu; rs_[m] = rstd; }
      float nx = dx*rstd*g4.x + b4.x;
      float ny = dy*rstd*g4.y + b4.y;
      float nz = dz*rstd*g4.z + b4.z;
      float nw = dw*rstd*g4.w + b4.w;
      int2 pv = { pk2(nx, ny), pk2(nz, nw) };
      int col = lane*4;
      *(int2*)&As[m][SWZ(m, col)] = pv;
    }
  }
  __syncthreads();

  const int m0 = (w >> 2) * 16;
  const int e0 = (w & 3) * 64;
  f32x4 acc4[4];
  #pragma unroll
  for (int j = 0; j < 4; ++j)
    #pragma unroll
    for (int r = 0; r < 4; ++r) acc4[j][r] = 0.f;

  for (int k0 = 0; k0 < 256; k0 += 64) {
    if (k0) __syncthreads();
    {
      const int ch = tid & 7;
      const int er = tid >> 3;
      #pragma unroll
      for (int p = 0; p < 4; ++p) {
        int e = p*64 + er;
        const float* wp = Wo + (size_t)e*256 + k0 + ch*8;
        float4 u0 = *(const float4*)wp;
        float4 u1 = *(const float4*)(wp + 4);
        int4 pk = { pk2(u0.x,u0.y), pk2(u0.z,u0.w), pk2(u1.x,u1.y), pk2(u1.z,u1.w) };
        *(int4*)&Ws[e][SWZ(e, ch*8)] = pk;
      }
    }
    __syncthreads();
    __builtin_amdgcn_s_setprio(1);
    #pragma unroll
    for (int ds_ = 0; ds_ < 2; ++ds_) {
      int ma = m0 + l15;
      bf16x8 af = *(const bf16x8*)&As[ma][SWZ(ma, k0 + ds_*32 + g*8)];
      #pragma unroll
      for (int j = 0; j < 4; ++j) {
        int er = e0 + j*16 + l15;
        bf16x8 bfv = *(const bf16x8*)&Ws[er][SWZ(er, ds_*32 + g*8)];
        acc4[j] = __builtin_amdgcn_mfma_f32_16x16x32_bf16(af, bfv, acc4[j], 0, 0, 0);
      }
    }
    __builtin_amdgcn_s_setprio(0);
  }
  __syncthreads();

  #pragma unroll
  for (int j = 0; j < 4; ++j) {
    int e = e0 + j*16 + l15;
    float bov = bo[e], g0e = g0v[e], b0e = b0v[e];
    #pragma unroll
    for (int r = 0; r < 4; ++r) {
      int m = m0 + g*4 + r;
      float xv = x[(size_t)(r0 + m)*256 + e];
      float resv = (xv - mu_[m]) * rs_[m] * g0e + b0e;
      float val = acc4[j][r] + bov;
      P[m*256 + e] = resv + fmaxf(val, 0.f);
    }
  }
  __syncthreads();

  {
    float4 g4 = *(const float4*)(g1v + lane*4);
    float4 b4 = *(const float4*)(b1v + lane*4);
    #pragma unroll
    for (int rr = 0; rr < 4; ++rr) {
      int m = w*4 + rr;
      float4 v = *(const float4*)&P[m*256 + lane*4];
      float s = v.x + v.y + v.z + v.w;
      #pragma unroll
      for (int mk = 1; mk <= 32; mk <<= 1) s += __shfl_xor(s, mk, 64);
      float mu = s * (1.0f/256.0f);
      float dx = v.x-mu, dy = v.y-mu, dz = v.z-mu, dw = v.w-mu;
      float qq = dx*dx + dy*dy + dz*dz + dw*dw;
      #pragma unroll
      for (int mk = 1; mk <= 32; mk <<= 1) qq += __shfl_xor(qq, mk, 64);
      float rstd = rsqrtf(qq * (1.0f/256.0f) + 1e-5f);
      float4 o;
      o.x = dx*rstd*g4.x + b4.x; o.y = dy*rstd*g4.y + b4.y;
      o.z = dz*rstd*g4.z + b4.z; o.w = dw*rstd*g4.w + b4.w;
      *(float4*)(y + (size_t)(r0 + m)*256 + lane*4) = o;
    }
  }
}

// ---------------------------------------------------------------------------
extern "C" void kernel_launch(void* const* d_in, const int* in_sizes, int n_in,
                              void* d_out, int out_size, void* d_ws, size_t ws_size,
                              hipStream_t stream) {
  const float* Q  = (const float*)d_in[0];
  const float* K  = (const float*)d_in[1];
  const float* Wq = (const float*)d_in[2];
  const float* bq = (const float*)d_in[3];
  const float* Wk = (const float*)d_in[4];
  const float* bk = (const float*)d_in[5];
  const float* Wv = (const float*)d_in[6];
  const float* bv = (const float*)d_in[7];
  const float* Wo = (const float*)d_in[8];
  const float* bo = (const float*)d_in[9];
  const float* g0 = (const float*)d_in[10];
  const float* b0 = (const float*)d_in[11];
  const float* g1 = (const float*)d_in[12];
  const float* b1 = (const float*)d_in[13];
  float* out = (float*)d_out;

  const size_t SZ = (size_t)4 * 2048 * 256;
  if (ws_size < 2 * SZ * sizeof(unsigned short)) return;  // need 8 MB

  unsigned short* kbf = (unsigned short*)d_ws;
  unsigned short* vtb = kbf + SZ;

  const int ATTN_LDS = 65536;  // K dbuf 32K + V dbuf 32K
  hipFuncSetAttribute((const void*)attn_mfma8,
                      hipFuncAttributeMaxDynamicSharedMemorySize, ATTN_LDS);

  proj_kernel<<<dim3(4, 128, 3), dim3(256), 0, stream>>>(
      Q, K, Wq, bq, Wk, bk, Wv, bv, out, kbf, vtb);
  attn_mfma8<<<dim3(512), dim3(256), ATTN_LDS, stream>>>(out, kbf, vtb, out);
  fused_out<<<dim3(256), dim3(512), 0, stream>>>(out, Wo, bo, g0, b0, g1, b1, out);
}